// Round 9
// baseline (3076.190 us; speedup 1.0000x reference)
//
#include <hip/hip_runtime.h>
#include <hip/hip_bf16.h>
#include <cstddef>

#define H    50
#define G4   200   // 4*H
#define TT   1024
#define BB   512
#define BLK  256   // threads per block: thread = gate row (200 active), 4 waves

__device__ __forceinline__ float sigm(float x) { return 1.0f / (1.0f + __expf(-x)); }
__device__ __forceinline__ float tanh_fast(float x) { return 1.0f - 2.0f / (__expf(2.0f * x) + 1.0f); }

// ---- 50 weights as individually NAMED scalar floats (single-register asm-tieable) ----
#define WD(P) \
  float P##00,P##01,P##02,P##03,P##04,P##05,P##06,P##07,P##08,P##09, \
        P##10,P##11,P##12,P##13,P##14,P##15,P##16,P##17,P##18,P##19, \
        P##20,P##21,P##22,P##23,P##24,P##25,P##26,P##27,P##28,P##29, \
        P##30,P##31,P##32,P##33,P##34,P##35,P##36,P##37,P##38,P##39, \
        P##40,P##41,P##42,P##43,P##44,P##45,P##46,P##47,P##48,P##49;

#define WL(P, src) do { const float* _s = (src); \
  P##00=_s[0];  P##01=_s[1];  P##02=_s[2];  P##03=_s[3];  P##04=_s[4];  \
  P##05=_s[5];  P##06=_s[6];  P##07=_s[7];  P##08=_s[8];  P##09=_s[9];  \
  P##10=_s[10]; P##11=_s[11]; P##12=_s[12]; P##13=_s[13]; P##14=_s[14]; \
  P##15=_s[15]; P##16=_s[16]; P##17=_s[17]; P##18=_s[18]; P##19=_s[19]; \
  P##20=_s[20]; P##21=_s[21]; P##22=_s[22]; P##23=_s[23]; P##24=_s[24]; \
  P##25=_s[25]; P##26=_s[26]; P##27=_s[27]; P##28=_s[28]; P##29=_s[29]; \
  P##30=_s[30]; P##31=_s[31]; P##32=_s[32]; P##33=_s[33]; P##34=_s[34]; \
  P##35=_s[35]; P##36=_s[36]; P##37=_s[37]; P##38=_s[38]; P##39=_s[39]; \
  P##40=_s[40]; P##41=_s[41]; P##42=_s[42]; P##43=_s[43]; P##44=_s[44]; \
  P##45=_s[45]; P##46=_s[46]; P##47=_s[47]; P##48=_s[48]; P##49=_s[49]; } while (0)

// In-loop keep-alive: tie each weight as a single-register "+v" operand ->
// values are loop-carried in VGPRs; reload/remat is illegal. Groups of <=13
// operands per asm statement (scalar ties are supported; float4 ties are not).
#define WKEEP(P) do { \
  asm volatile("" : "+v"(P##00),"+v"(P##01),"+v"(P##02),"+v"(P##03),"+v"(P##04), \
                    "+v"(P##05),"+v"(P##06),"+v"(P##07),"+v"(P##08),"+v"(P##09), \
                    "+v"(P##10),"+v"(P##11),"+v"(P##12)); \
  asm volatile("" : "+v"(P##13),"+v"(P##14),"+v"(P##15),"+v"(P##16),"+v"(P##17), \
                    "+v"(P##18),"+v"(P##19),"+v"(P##20),"+v"(P##21),"+v"(P##22), \
                    "+v"(P##23),"+v"(P##24),"+v"(P##25)); \
  asm volatile("" : "+v"(P##26),"+v"(P##27),"+v"(P##28),"+v"(P##29),"+v"(P##30), \
                    "+v"(P##31),"+v"(P##32),"+v"(P##33),"+v"(P##34),"+v"(P##35), \
                    "+v"(P##36),"+v"(P##37),"+v"(P##38)); \
  asm volatile("" : "+v"(P##39),"+v"(P##40),"+v"(P##41),"+v"(P##42),"+v"(P##43), \
                    "+v"(P##44),"+v"(P##45),"+v"(P##46),"+v"(P##47),"+v"(P##48), \
                    "+v"(P##49)); \
} while (0)

// vp: 16B-aligned LDS float*; vector LDS reads (ds_read_b128) into float4
// temporaries, scalar FMAs into 4 independent accumulator chains.
#define WDOT(P, vp, out) do { \
  const float4* _vp4 = (const float4*)(vp); \
  float4 _t0=_vp4[0],_t1=_vp4[1],_t2=_vp4[2], _t3=_vp4[3], _t4=_vp4[4],  _t5=_vp4[5], \
         _t6=_vp4[6],_t7=_vp4[7],_t8=_vp4[8], _t9=_vp4[9], _t10=_vp4[10],_t11=_vp4[11]; \
  float _e48=(vp)[48], _e49=(vp)[49]; \
  float _a0=0.f,_a1=0.f,_a2=0.f,_a3=0.f; \
  _a0=__fmaf_rn(P##00,_t0.x,_a0);  _a1=__fmaf_rn(P##01,_t0.y,_a1); \
  _a2=__fmaf_rn(P##02,_t0.z,_a2);  _a3=__fmaf_rn(P##03,_t0.w,_a3); \
  _a0=__fmaf_rn(P##04,_t1.x,_a0);  _a1=__fmaf_rn(P##05,_t1.y,_a1); \
  _a2=__fmaf_rn(P##06,_t1.z,_a2);  _a3=__fmaf_rn(P##07,_t1.w,_a3); \
  _a0=__fmaf_rn(P##08,_t2.x,_a0);  _a1=__fmaf_rn(P##09,_t2.y,_a1); \
  _a2=__fmaf_rn(P##10,_t2.z,_a2);  _a3=__fmaf_rn(P##11,_t2.w,_a3); \
  _a0=__fmaf_rn(P##12,_t3.x,_a0);  _a1=__fmaf_rn(P##13,_t3.y,_a1); \
  _a2=__fmaf_rn(P##14,_t3.z,_a2);  _a3=__fmaf_rn(P##15,_t3.w,_a3); \
  _a0=__fmaf_rn(P##16,_t4.x,_a0);  _a1=__fmaf_rn(P##17,_t4.y,_a1); \
  _a2=__fmaf_rn(P##18,_t4.z,_a2);  _a3=__fmaf_rn(P##19,_t4.w,_a3); \
  _a0=__fmaf_rn(P##20,_t5.x,_a0);  _a1=__fmaf_rn(P##21,_t5.y,_a1); \
  _a2=__fmaf_rn(P##22,_t5.z,_a2);  _a3=__fmaf_rn(P##23,_t5.w,_a3); \
  _a0=__fmaf_rn(P##24,_t6.x,_a0);  _a1=__fmaf_rn(P##25,_t6.y,_a1); \
  _a2=__fmaf_rn(P##26,_t6.z,_a2);  _a3=__fmaf_rn(P##27,_t6.w,_a3); \
  _a0=__fmaf_rn(P##28,_t7.x,_a0);  _a1=__fmaf_rn(P##29,_t7.y,_a1); \
  _a2=__fmaf_rn(P##30,_t7.z,_a2);  _a3=__fmaf_rn(P##31,_t7.w,_a3); \
  _a0=__fmaf_rn(P##32,_t8.x,_a0);  _a1=__fmaf_rn(P##33,_t8.y,_a1); \
  _a2=__fmaf_rn(P##34,_t8.z,_a2);  _a3=__fmaf_rn(P##35,_t8.w,_a3); \
  _a0=__fmaf_rn(P##36,_t9.x,_a0);  _a1=__fmaf_rn(P##37,_t9.y,_a1); \
  _a2=__fmaf_rn(P##38,_t9.z,_a2);  _a3=__fmaf_rn(P##39,_t9.w,_a3); \
  _a0=__fmaf_rn(P##40,_t10.x,_a0); _a1=__fmaf_rn(P##41,_t10.y,_a1); \
  _a2=__fmaf_rn(P##42,_t10.z,_a2); _a3=__fmaf_rn(P##43,_t10.w,_a3); \
  _a0=__fmaf_rn(P##44,_t11.x,_a0); _a1=__fmaf_rn(P##45,_t11.y,_a1); \
  _a2=__fmaf_rn(P##46,_t11.z,_a2); _a3=__fmaf_rn(P##47,_t11.w,_a3); \
  _a0=__fmaf_rn(P##48,_e48,_a0);   _a1=__fmaf_rn(P##49,_e49,_a1); \
  (out) += (_a0+_a2)+(_a1+_a3); } while (0)

// MODE 0: first layer (scalar x input, write h-seq)
// MODE 1: middle layer (vector input, write h-seq; in-place on ws is safe)
// MODE 2: last layer (vector input, no h-seq write, fused dense head)
template <int MODE>
__global__ __launch_bounds__(BLK) __attribute__((amdgpu_waves_per_eu(2, 2)))
void lstm_kernel(
    const float* __restrict__ xin,     // MODE0: x [B][T]; else h_prev [B][T][H]
    const float* __restrict__ w_ih,    // [G4][H] (MODE0: [G4][1])
    const float* __restrict__ w_hh,    // [G4][H]
    const float* __restrict__ b_ih,    // [G4]
    const float* __restrict__ b_hh,    // [G4]
    float* __restrict__ hout,          // [B][T][H]  (MODE 0,1)
    const float* __restrict__ w_dense, // [H]    (MODE 2)
    const float* __restrict__ b_dense, // [1]    (MODE 2)
    float* __restrict__ out)           // [B]    (MODE 2)
{
    const int b   = blockIdx.x;
    const int tid = threadIdx.x;
    const int wv  = tid >> 6;   // wave 0..3
    const int ln  = tid & 63;   // lane
    const int p   = tid;        // gate row (<200 active)
    const bool active = (p < G4);
    const int pr  = active ? p : (G4 - 1);   // clamp for safe loads; garbage unused

    __shared__ __align__(16) float h_s[4][64];     // per-wave h copy (same-wave dep only)
    __shared__ float gates_s[2][G4];               // double-buffered gate pre-activations
    __shared__ __align__(16) float xin_s[2][64];   // MODE 1,2: double-buffered x_t
    __shared__ float x_s[MODE == 0 ? TT : 1];      // MODE 0: whole input row (4 KB)

    // ---- weights into named scalar registers ----
    WD(wh) WD(wx)
    float wxs = 0.f;
    WL(wh, w_hh + pr * H);
    if (MODE == 0) {
        wxs = w_ih[pr];
    } else {
        WL(wx, w_ih + pr * H);
    }
    const float bias = b_ih[pr] + b_hh[pr];
    float wd_r = 0.f;
    if (MODE == 2 && ln < H) wd_r = w_dense[ln];

    const float* __restrict__ xrow = xin + (size_t)b * TT * (MODE == 0 ? 1 : H);

    // ---- init LDS state + stage first inputs ----
    h_s[wv][ln] = 0.f;
    const int  sp     = tid - G4;                   // 0..49 for prefetch threads
    const bool preTh  = (MODE != 0) && (sp >= 0) && (sp < H);
    float xpre_cur = 0.f;                           // holds x_{t+1} row element
    if (MODE == 0) {
        for (int i = tid; i < TT; i += BLK) x_s[i] = xrow[i];
    } else {
        if (tid < H) xin_s[0][tid] = xrow[tid];     // x_0
        if (preTh)   xpre_cur = xrow[(size_t)1 * H + sp];  // x_1 -> register
    }
    float c_r = 0.f;     // cell state (lanes < H, replicated per wave)
    float hval = 0.f;
    __syncthreads();

    for (int t = 0; t < TT; t++) {
        const int pbuf = t & 1;

        // pin weights in VGPRs this iteration (loop-carried; no remat/reload)
        WKEEP(wh);
        if (MODE != 0) WKEEP(wx);

        // ---- issue prefetch for t+2 (consumed NEXT iteration: full step of cover) ----
        float xpre_next = 0.f;
        if (preTh && t + 2 < TT) xpre_next = xrow[(size_t)(t + 2) * H + sp];

        // ---- phase 1: gate pre-activation (all lanes compute; LDS reads broadcast) ----
        float acc = bias;
        WDOT(wh, h_s[wv], acc);
        if (MODE == 0) {
            acc = __fmaf_rn(wxs, x_s[t], acc);
        } else {
            WDOT(wx, xin_s[pbuf], acc);
        }
        if (active) gates_s[pbuf][p] = acc;

        // ---- land x_{t+1} (loaded LAST iteration -> latency fully hidden) ----
        if (preTh && t + 1 < TT) xin_s[pbuf ^ 1][sp] = xpre_cur;

        __syncthreads();   // the ONLY barrier per step

        // ---- phase 2: elementwise update, redundant in every wave ----
        if (ln < H) {
            float iv = sigm(gates_s[pbuf][ln]);
            float fv = sigm(gates_s[pbuf][H + ln]);
            float gv = tanh_fast(gates_s[pbuf][2 * H + ln]);
            float ov = sigm(gates_s[pbuf][3 * H + ln]);
            c_r = __fmaf_rn(fv, c_r, iv * gv);
            hval = ov * tanh_fast(c_r);
            h_s[wv][ln] = hval;
            if (MODE != 2 && wv == 0)
                hout[(size_t)b * TT * H + (size_t)t * H + ln] = hval;
        }
        xpre_cur = xpre_next;
        // next phase-1 reads h_s[wv]: same-wave dependency -> no second barrier
    }

    // ---- dense head (MODE 2): out[b] = h_last . w_dense + b_dense ----
    if (MODE == 2 && wv == 0) {
        float v = (ln < H) ? hval * wd_r : 0.f;
#pragma unroll
        for (int off = 32; off > 0; off >>= 1) v += __shfl_down(v, off, 64);
        if (ln == 0) out[b] = v + b_dense[0];
    }
}

extern "C" void kernel_launch(void* const* d_in, const int* in_sizes, int n_in,
                              void* d_out, int out_size, void* d_ws, size_t ws_size,
                              hipStream_t stream) {
    const float* x     = (const float*)d_in[0];
    const float* wih1  = (const float*)d_in[1];
    const float* whh1  = (const float*)d_in[2];
    const float* bih1  = (const float*)d_in[3];
    const float* bhh1  = (const float*)d_in[4];
    const float* wih2  = (const float*)d_in[5];
    const float* whh2  = (const float*)d_in[6];
    const float* bih2  = (const float*)d_in[7];
    const float* bhh2  = (const float*)d_in[8];
    const float* wih3  = (const float*)d_in[9];
    const float* whh3  = (const float*)d_in[10];
    const float* bih3  = (const float*)d_in[11];
    const float* bhh3  = (const float*)d_in[12];
    const float* wd    = (const float*)d_in[13];
    const float* bd    = (const float*)d_in[14];
    float* outp = (float*)d_out;
    float* hbuf = (float*)d_ws;   // [B][T][H] fp32, used in-place by all layers

    lstm_kernel<0><<<BB, BLK, 0, stream>>>(x,    wih1, whh1, bih1, bhh1, hbuf, nullptr, nullptr, nullptr);
    lstm_kernel<1><<<BB, BLK, 0, stream>>>(hbuf, wih2, whh2, bih2, bhh2, hbuf, nullptr, nullptr, nullptr);
    lstm_kernel<2><<<BB, BLK, 0, stream>>>(hbuf, wih3, whh3, bih3, bhh3, nullptr, wd, bd, outp);
}

// Round 10
// 2267.054 us; speedup vs baseline: 1.3569x; 1.3569x over previous
//
#include <hip/hip_runtime.h>
#include <hip/hip_bf16.h>
#include <cstddef>

#define H    50
#define G4   200   // 4*H
#define TT   1024
#define BB   512
#define BLK  512   // 8 waves: waves 0..3 = h-waves (lane=(unit,qK)), 4..7 = x-waves

__device__ __forceinline__ float sigm(float x) { return 1.0f / (1.0f + __expf(-x)); }
__device__ __forceinline__ float tanh_fast(float x) { return 1.0f - 2.0f / (__expf(2.0f * x) + 1.0f); }

// ---- 13 named scalar floats ----
#define D13(P) float P##0,P##1,P##2,P##3,P##4,P##5,P##6,P##7,P##8,P##9,P##10,P##11,P##12

// weight row slice: k = K0..K0+12, zero-padded past H (K0 = 13*q, q=3 has 2 pads)
#define WL13(P, WPTR, ROW, K0) do { const float* _w = (WPTR) + (size_t)(ROW) * H; const int _k = (K0); \
  P##0 =(_k+ 0<H)?_w[_k+ 0]:0.f; P##1 =(_k+ 1<H)?_w[_k+ 1]:0.f; P##2 =(_k+ 2<H)?_w[_k+ 2]:0.f; \
  P##3 =(_k+ 3<H)?_w[_k+ 3]:0.f; P##4 =(_k+ 4<H)?_w[_k+ 4]:0.f; P##5 =(_k+ 5<H)?_w[_k+ 5]:0.f; \
  P##6 =(_k+ 6<H)?_w[_k+ 6]:0.f; P##7 =(_k+ 7<H)?_w[_k+ 7]:0.f; P##8 =(_k+ 8<H)?_w[_k+ 8]:0.f; \
  P##9 =(_k+ 9<H)?_w[_k+ 9]:0.f; P##10=(_k+10<H)?_w[_k+10]:0.f; P##11=(_k+11<H)?_w[_k+11]:0.f; \
  P##12=(_k+12<H)?_w[_k+12]:0.f; } while (0)

// h slice from padded LDS (h_s has 52 entries; 50,51 are zero) — broadcast reads
#define HT13(P, HS, K0) float P##0=(HS)[(K0)+0], P##1=(HS)[(K0)+1], P##2 =(HS)[(K0)+2], \
  P##3=(HS)[(K0)+3], P##4=(HS)[(K0)+4],  P##5 =(HS)[(K0)+5],  P##6 =(HS)[(K0)+6], \
  P##7=(HS)[(K0)+7], P##8=(HS)[(K0)+8],  P##9 =(HS)[(K0)+9],  P##10=(HS)[(K0)+10], \
  P##11=(HS)[(K0)+11], P##12=(HS)[(K0)+12]

#define DOT13(W, X, A) do { \
  A=__fmaf_rn(W##0,X##0,A);  A=__fmaf_rn(W##1,X##1,A);  A=__fmaf_rn(W##2,X##2,A); \
  A=__fmaf_rn(W##3,X##3,A);  A=__fmaf_rn(W##4,X##4,A);  A=__fmaf_rn(W##5,X##5,A); \
  A=__fmaf_rn(W##6,X##6,A);  A=__fmaf_rn(W##7,X##7,A);  A=__fmaf_rn(W##8,X##8,A); \
  A=__fmaf_rn(W##9,X##9,A);  A=__fmaf_rn(W##10,X##10,A); A=__fmaf_rn(W##11,X##11,A); \
  A=__fmaf_rn(W##12,X##12,A); } while (0)

// x-wave global loads of x_step slice (BASE already includes k0x); pads re-read k0x
#define XL13(P, BASE) do { const size_t _b = (BASE); \
  P##0 = xrow[_b];                          P##1 =(k0x+ 1<H)?xrow[_b+ 1]:xrow[_b]; \
  P##2 =(k0x+ 2<H)?xrow[_b+ 2]:xrow[_b];    P##3 =(k0x+ 3<H)?xrow[_b+ 3]:xrow[_b]; \
  P##4 =(k0x+ 4<H)?xrow[_b+ 4]:xrow[_b];    P##5 =(k0x+ 5<H)?xrow[_b+ 5]:xrow[_b]; \
  P##6 =(k0x+ 6<H)?xrow[_b+ 6]:xrow[_b];    P##7 =(k0x+ 7<H)?xrow[_b+ 7]:xrow[_b]; \
  P##8 =(k0x+ 8<H)?xrow[_b+ 8]:xrow[_b];    P##9 =(k0x+ 9<H)?xrow[_b+ 9]:xrow[_b]; \
  P##10=(k0x+10<H)?xrow[_b+10]:xrow[_b];    P##11=(k0x+11<H)?xrow[_b+11]:xrow[_b]; \
  P##12=(k0x+12<H)?xrow[_b+12]:xrow[_b]; } while (0)

// x-wave: 4 partial dots from SRC regs -> xw_s[NB]
#define XCOMP(SRC, NB) do { float _p0=0.f,_p1=0.f,_p2=0.f,_p3=0.f; \
  DOT13(wA,SRC,_p0); DOT13(wB,SRC,_p1); DOT13(wC,SRC,_p2); DOT13(wD,SRC,_p3); \
  xw_s[NB][0][ux][qx]=_p0; xw_s[NB][1][ux][qx]=_p1; \
  xw_s[NB][2][ux][qx]=_p2; xw_s[NB][3][ux][qx]=_p3; } while (0)

// One time step. CUR compile-time 0/1. XSRC holds x_{T+1}; XDST receives x_{T+2}.
#define STEP(CUR, T, XSRC, XDST) do { \
  if (hw) { \
    HT13(ht, h_s[CUR], k0h); \
    float a0=0.f, a1=0.f, a2=0.f, a3=0.f; \
    DOT13(wA, ht, a0); DOT13(wB, ht, a1); DOT13(wC, ht, a2); DOT13(wD, ht, a3); \
    if (MODE != 0) { \
      a0 += xw_s[CUR][0][uh][qh]; a1 += xw_s[CUR][1][uh][qh]; \
      a2 += xw_s[CUR][2][uh][qh]; a3 += xw_s[CUR][3][uh][qh]; \
    } \
    a0 += __shfl_xor(a0, 1); a0 += __shfl_xor(a0, 2); \
    a1 += __shfl_xor(a1, 1); a1 += __shfl_xor(a1, 2); \
    a2 += __shfl_xor(a2, 1); a2 += __shfl_xor(a2, 2); \
    a3 += __shfl_xor(a3, 1); a3 += __shfl_xor(a3, 2); \
    if (MODE == 0) { float _xt = x_s[T]; \
      a0 = __fmaf_rn(wi0,_xt,a0); a1 = __fmaf_rn(wi1,_xt,a1); \
      a2 = __fmaf_rn(wi2,_xt,a2); a3 = __fmaf_rn(wi3,_xt,a3); } \
    float iv = sigm(a0 + bb0), fv = sigm(a1 + bb1); \
    float gv = tanh_fast(a2 + bb2), ov = sigm(a3 + bb3); \
    c_r  = __fmaf_rn(fv, c_r, iv * gv); \
    hval = ov * tanh_fast(c_r); \
    if (hvalid) { \
      h_s[(CUR)^1][uh] = hval; \
      if (MODE != 2) hout[hob + (size_t)(T) * H + uh] = hval; \
    } \
  } else if (MODE != 0) { \
    if ((T) + 2 < TT) { XL13(XDST, (size_t)((T)+2) * H + k0x); } \
    if ((T) + 1 < TT) { XCOMP(XSRC, (CUR)^1); } \
  } \
  __syncthreads(); \
} while (0)

// MODE 0: first layer (scalar x); MODE 1: middle; MODE 2: last + dense head
template <int MODE>
__global__ __launch_bounds__(BLK, 4) __attribute__((amdgpu_waves_per_eu(4, 4)))
void lstm_kernel(
    const float* __restrict__ xin,
    const float* __restrict__ w_ih,    // [G4][H] (MODE0: [G4][1])
    const float* __restrict__ w_hh,    // [G4][H]
    const float* __restrict__ b_ih,    // [G4]
    const float* __restrict__ b_hh,    // [G4]
    float* __restrict__ hout,          // [B][T][H] (MODE 0,1)
    const float* __restrict__ w_dense, // [H]   (MODE 2)
    const float* __restrict__ b_dense, // [1]   (MODE 2)
    float* __restrict__ out)           // [B]   (MODE 2)
{
    const int b   = blockIdx.x;
    const int tid = threadIdx.x;
    const int wv  = tid >> 6;
    const int ln  = tid & 63;
    const bool hw = (wv < 4);                    // h-wave role

    // h-wave mapping: unit uh = wv*16 + ln/4 (valid < 50), K-quarter qh = ln&3
    const int uh  = (wv & 3) * 16 + (ln >> 2);
    const int qh  = ln & 3;
    const int k0h = 13 * qh;
    const int uch = (uh < H) ? uh : (H - 1);
    const bool hvalid = hw && (uh < H) && (qh == 0);

    // x-wave mapping (same shape)
    const int ux  = uh, qx = qh, k0x = k0h, ucx = uch;

    __shared__ float h_s[2][52];                 // padded: [50],[51] stay 0
    __shared__ float xw_s[2][4][64][4];          // [buf][gate][unit][q] partial x-dots
    __shared__ float x_s[MODE == 0 ? TT : 1];    // MODE0: whole scalar input row

    // ---- weights: 4 gate rows x 13-slice = 52 named scalars (resident scale) ----
    D13(wA); D13(wB); D13(wC); D13(wD);
    D13(xa); D13(xb);                            // x-wave double-buffered x slices
    float wi0 = 0.f, wi1 = 0.f, wi2 = 0.f, wi3 = 0.f;  // MODE0 scalar x-weights
    float bb0 = 0.f, bb1 = 0.f, bb2 = 0.f, bb3 = 0.f;

    const float* __restrict__ xrow = xin + (size_t)b * TT * (MODE == 0 ? 1 : H);
    const size_t hob = (size_t)b * TT * H;

    if (hw) {
        WL13(wA, w_hh, 0 * H + uch, k0h);
        WL13(wB, w_hh, 1 * H + uch, k0h);
        WL13(wC, w_hh, 2 * H + uch, k0h);
        WL13(wD, w_hh, 3 * H + uch, k0h);
        bb0 = b_ih[0 * H + uch] + b_hh[0 * H + uch];
        bb1 = b_ih[1 * H + uch] + b_hh[1 * H + uch];
        bb2 = b_ih[2 * H + uch] + b_hh[2 * H + uch];
        bb3 = b_ih[3 * H + uch] + b_hh[3 * H + uch];
        if (MODE == 0) {
            wi0 = w_ih[0 * H + uch]; wi1 = w_ih[1 * H + uch];
            wi2 = w_ih[2 * H + uch]; wi3 = w_ih[3 * H + uch];
        }
    } else if (MODE != 0) {
        WL13(wA, w_ih, 0 * H + ucx, k0x);
        WL13(wB, w_ih, 1 * H + ucx, k0x);
        WL13(wC, w_ih, 2 * H + ucx, k0x);
        WL13(wD, w_ih, 3 * H + ucx, k0x);
    }
    float wdr = 0.f;
    if (MODE == 2 && wv == 0 && ln < H) wdr = w_dense[ln];

    // ---- init LDS ----
    if (tid < 104) (&h_s[0][0])[tid] = 0.f;
    if (MODE == 0) {
        for (int i = tid; i < TT; i += BLK) x_s[i] = xrow[i];
    } else if (!hw) {
        XL13(xb, (size_t)0 * H + k0x);   // x_0 (scratch)
        XCOMP(xb, 0);                    // xw partials for t=0
        XL13(xa, (size_t)1 * H + k0x);   // x_1 for STEP(0, t=0)
    }
    float c_r = 0.f, hval = 0.f;
    __syncthreads();

    for (int t = 0; t < TT; t += 2) {
        STEP(0, t,     xa, xb);
        STEP(1, t + 1, xb, xa);
    }
    // final h is in h_s[0] (TT even)

    if (MODE == 2 && wv == 0) {
        float v = (ln < H) ? h_s[0][ln] * wdr : 0.f;
#pragma unroll
        for (int off = 32; off > 0; off >>= 1) v += __shfl_down(v, off, 64);
        if (ln == 0) out[b] = v + b_dense[0];
    }
}

extern "C" void kernel_launch(void* const* d_in, const int* in_sizes, int n_in,
                              void* d_out, int out_size, void* d_ws, size_t ws_size,
                              hipStream_t stream) {
    const float* x     = (const float*)d_in[0];
    const float* wih1  = (const float*)d_in[1];
    const float* whh1  = (const float*)d_in[2];
    const float* bih1  = (const float*)d_in[3];
    const float* bhh1  = (const float*)d_in[4];
    const float* wih2  = (const float*)d_in[5];
    const float* whh2  = (const float*)d_in[6];
    const float* bih2  = (const float*)d_in[7];
    const float* bhh2  = (const float*)d_in[8];
    const float* wih3  = (const float*)d_in[9];
    const float* whh3  = (const float*)d_in[10];
    const float* bih3  = (const float*)d_in[11];
    const float* bhh3  = (const float*)d_in[12];
    const float* wd    = (const float*)d_in[13];
    const float* bd    = (const float*)d_in[14];
    float* outp = (float*)d_out;
    float* hbuf = (float*)d_ws;   // [B][T][H] fp32, in-place across layers

    lstm_kernel<0><<<BB, BLK, 0, stream>>>(x,    wih1, whh1, bih1, bhh1, hbuf, nullptr, nullptr, nullptr);
    lstm_kernel<1><<<BB, BLK, 0, stream>>>(hbuf, wih2, whh2, bih2, bhh2, hbuf, nullptr, nullptr, nullptr);
    lstm_kernel<2><<<BB, BLK, 0, stream>>>(hbuf, wih3, whh3, bih3, bhh3, nullptr, wd, bd, outp);
}